// Round 9
// baseline (255.570 us; speedup 1.0000x reference)
//
#include <hip/hip_runtime.h>
#include <hip/hip_bf16.h>
#include <math.h>
#include <stdint.h>

#define Bb 16
#define Tt 28
#define Nn 2048
#define Hh 32
#define LAGS 8
#define LN_EPS 1e-5f
#define PSTR 40                      // P row stride (shorts)

typedef float f4 __attribute__((ext_vector_type(4)));
typedef short s8v __attribute__((ext_vector_type(8)));
typedef unsigned short u16x4 __attribute__((ext_vector_type(4)));
typedef unsigned short u16x8 __attribute__((ext_vector_type(8)));

__device__ __forceinline__ float b2f(unsigned short u) {
    union { unsigned uu; float ff; } x; x.uu = ((unsigned)u) << 16; return x.ff;
}
__device__ __forceinline__ unsigned short f2b(float f) {
    unsigned u = __float_as_uint(f);
    u += 0x7FFFu + ((u >> 16) & 1u);   // RNE
    return (unsigned short)(u >> 16);
}

// ---------- adj fp32 -> bf16 scaled by geo*5, fragment-tile layout (LDS-staged) ----
// adjF[((n>>4)*512 + (m>>2))*64 + (n&15)*4 + (m&3)]
// block: n-tile g = bid>>2 (16 rows), m-chunk q = bid&3 (512 m). 256 threads.
__global__ void k_adjprep(const float* __restrict__ adj, const float* __restrict__ geo_w,
                          unsigned short* __restrict__ adjF) {
    __shared__ float T[16][516];
    float geo = 1.f / (1.f + __expf(-geo_w[0]));
    float cg = geo * 5.f;
    int tid = threadIdx.x;
    int g = blockIdx.x >> 2, q = blockIdx.x & 3;
    int n0 = g * 16, m0 = q * 512;
    #pragma unroll
    for (int r = 0; r < 16; ++r) {
        T[r][tid] = adj[(size_t)(n0 + r) * Nn + m0 + tid];
        T[r][tid + 256] = adj[(size_t)(n0 + r) * Nn + m0 + tid + 256];
    }
    __syncthreads();
    unsigned short* region = adjF + ((size_t)g * 512 + q * 128) * 64;
    #pragma unroll
    for (int i = 0; i < 4; ++i) {
        int e0 = (i * 256 + tid) * 8;
        u16x8 w;
        #pragma unroll
        for (int j = 0; j < 8; ++j) {
            int e = e0 + j;
            int mq = e >> 6, nl = (e >> 2) & 15, mm = e & 3;
            w[j] = f2b(cg * T[nl][mq * 4 + mm]);
        }
        *(u16x8*)(region + e0) = w;
    }
}

// ---------------- delayed signal (f32) ----------------
__global__ void k_delayed(const float* __restrict__ x,
                          const float* __restrict__ dlog,
                          float* __restrict__ dsg) {
    int idx = blockIdx.x * blockDim.x + threadIdx.x; // over B*N
    float w[LAGS];
    float m = -1e30f;
    #pragma unroll
    for (int t = 0; t < LAGS; ++t) m = fmaxf(m, dlog[t]);
    float s = 0.f;
    #pragma unroll
    for (int t = 0; t < LAGS; ++t) { w[t] = __expf(dlog[t] - m); s += w[t]; }
    float inv = 1.f / s;
    if (idx >= Bb * Nn) return;
    int b = idx / Nn, n = idx % Nn;
    float acc = 0.f;
    #pragma unroll
    for (int t = 0; t < LAGS; ++t)
        acc += (w[t] * inv) * x[(size_t)b * Tt * Nn + (size_t)(Tt - 1 - t) * Nn + n];
    dsg[idx] = acc;
}

// ---------- fused QKV: Q (row-major, pre-scaled by cs), K,V fragment layouts ----------
// Kf[((b*128 + (m>>4))*4 + (k>>3))*16 + (m&15)][8]  (k&7 inner)
// Vf[((b*64 + (m>>5))*4 + ((m>>3)&3))*32 + h][8]    (m&7 inner)
__global__ void k_qkv(const float* __restrict__ feat,
                      const float* __restrict__ Wq, const float* __restrict__ bq,
                      const float* __restrict__ Wk, const float* __restrict__ bk,
                      const float* __restrict__ Wv, const float* __restrict__ bv,
                      const float* __restrict__ geo_w,
                      unsigned short* __restrict__ Qbf, unsigned short* __restrict__ Kf,
                      unsigned short* __restrict__ Vf) {
    __shared__ float WqT[Hh][Hh + 1], WkT[Hh][Hh + 1], WvT[Hh][Hh + 1];
    __shared__ float f[8][Hh];
    __shared__ __align__(16) unsigned short VT8[Hh][8];
    int tid = threadIdx.x;
    for (int i = tid; i < Hh * Hh; i += 256) {
        int h = i >> 5, k = i & 31;
        WqT[k][h] = Wq[i];
        WkT[k][h] = Wk[i];
        WvT[k][h] = Wv[i];
    }
    float geo = 1.f / (1.f + __expf(-geo_w[0]));
    float cs = (1.f - geo) * 0.17677669529663687f;   // (1-geo)/sqrt(32)
    int n0 = blockIdx.x * 8;
    f[tid >> 5][tid & 31] = feat[(size_t)n0 * Hh + tid];
    __syncthreads();
    int lr = tid >> 5, h = tid & 31;
    float aq = bq[h], ak = bk[h], av = bv[h];
    #pragma unroll
    for (int k = 0; k < Hh; ++k) {
        float fv = f[lr][k];
        aq += fv * WqT[k][h];
        ak += fv * WkT[k][h];
        av += fv * WvT[k][h];
    }
    Qbf[(size_t)(n0 + lr) * Hh + h] = f2b(aq * cs);
    int b = n0 >> 11, mloc = (n0 & 2047) + lr;
    size_t kaddr = ((((size_t)b * 128 + (mloc >> 4)) * 4 + (h >> 3)) * 16 + (mloc & 15)) * 8 + (h & 7);
    Kf[kaddr] = f2b(ak);
    VT8[h][lr] = f2b(av);
    __syncthreads();
    if (tid < 32) {
        int mloc0 = n0 & 2047;
        size_t vaddr = ((((size_t)b * 64 + (mloc0 >> 5)) * 4 + ((mloc0 >> 3) & 3)) * 32 + tid) * 8;
        *(u16x8*)(Vf + vaddr) = *(const u16x8*)&VT8[tid][0];
    }
}

// ---------------- MFMA attention: 4 waves/block, grid 1024, max occupancy ---------
// Wave wh = wid (0..3) owns the 32-m quarter of each 128-chunk; block owns 32 n-cols.
// Scores: mfma(K_frag, Q_scaled, C = adj_frag) -> __expf -> P (LDS) -> PV mfma.
__global__ __launch_bounds__(256, 8)
void k_attn(const unsigned short* __restrict__ Qbf,
            const unsigned short* __restrict__ Kf,
            const unsigned short* __restrict__ Vf,
            const unsigned short* __restrict__ adjF,
            const float* __restrict__ dsg,
            const float* __restrict__ feat,
            unsigned short* __restrict__ comb) {
    __shared__ __align__(16) unsigned short Pt[4][32 * PSTR];   // 10240 B; reused as merge scratch

    int tid = threadIdx.x;
    int wid = tid >> 6, lane = tid & 63;
    int nl = lane & 15, g4 = lane >> 4;
    int wh = wid;

    // XCD-partitioned swizzle: xcd = bid&7 -> (n-quarter = xcd>>1, batch-half = xcd&1)
    int bid = blockIdx.x;
    int xcd = bid & 7, r = bid >> 3;            // r: 0..127
    int b = ((xcd & 1) << 3) + (r & 7);
    int nt32 = ((xcd >> 1) << 4) + (r >> 3);    // 0..63
    int n0w = nt32 * 32;

    // Q B-fragments (col = n = nl, k = g4*8+j); Q pre-scaled by cs
    s8v qf[2];
    #pragma unroll
    for (int nt = 0; nt < 2; ++nt)
        qf[nt] = *(const s8v*)(Qbf + (((size_t)b * Nn + n0w + nt * 16 + nl) << 5) + g4 * 8);

    f4 pacc[2][2];
    #pragma unroll
    for (int nt = 0; nt < 2; ++nt)
        #pragma unroll
        for (int t = 0; t < 2; ++t) pacc[nt][t] = (f4){0.f, 0.f, 0.f, 0.f};
    float ps[2] = {0.f, 0.f}, prop[2] = {0.f, 0.f};

    const unsigned short* Kb = Kf + (size_t)b * 128 * 4 * 16 * 8;
    const unsigned short* Vb = Vf + (size_t)b * 64 * 4 * 32 * 8;
    const float* dsb = dsg + (size_t)b * Nn;
    unsigned short* Pw = Pt[wid];

    struct Frag {
        s8v kf0, kf1, vf0, vf1;
        f4 dv0, dv1;
        u16x4 a00, a01, a10, a11;
    };

    auto load = [&](Frag& F, int c) {
        int mw = c * 128 + wh * 32;
        F.kf0 = *(const s8v*)(Kb + ((((size_t)(mw >> 4) + 0) * 4 + g4) * 16 + nl) * 8);
        F.kf1 = *(const s8v*)(Kb + ((((size_t)(mw >> 4) + 1) * 4 + g4) * 16 + nl) * 8);
        F.vf0 = *(const s8v*)(Vb + (((size_t)(mw >> 5) * 4 + g4) * 32 + 0 * 16 + nl) * 8);
        F.vf1 = *(const s8v*)(Vb + (((size_t)(mw >> 5) * 4 + g4) * 32 + 1 * 16 + nl) * 8);
        F.dv0 = *(const f4*)(dsb + mw + g4 * 4);
        F.dv1 = *(const f4*)(dsb + mw + 16 + g4 * 4);
        size_t arow0 = (size_t)((n0w >> 4) + 0) * 512 + (mw >> 2);
        size_t arow1 = (size_t)((n0w >> 4) + 1) * 512 + (mw >> 2);
        F.a00 = *(const u16x4*)(adjF + (arow0 + 0 + g4) * 64 + nl * 4);
        F.a01 = *(const u16x4*)(adjF + (arow0 + 4 + g4) * 64 + nl * 4);
        F.a10 = *(const u16x4*)(adjF + (arow1 + 0 + g4) * 64 + nl * 4);
        F.a11 = *(const u16x4*)(adjF + (arow1 + 4 + g4) * 64 + nl * 4);
    };

    auto mkC = [&](u16x4 av) -> f4 {
        f4 C;
        C[0] = b2f(av[0]); C[1] = b2f(av[1]); C[2] = b2f(av[2]); C[3] = b2f(av[3]);
        return C;
    };

    auto SM = [&](f4 sc, f4 dv, int nt, int mg) {
        float p0 = __expf(sc[0]), p1 = __expf(sc[1]);
        float p2 = __expf(sc[2]), p3 = __expf(sc[3]);
        ps[nt] += (p0 + p1) + (p2 + p3);
        prop[nt] += p0 * dv[0] + p1 * dv[1] + p2 * dv[2] + p3 * dv[3];
        uint2 w;
        w.x = (unsigned)f2b(p0) | ((unsigned)f2b(p1) << 16);
        w.y = (unsigned)f2b(p2) | ((unsigned)f2b(p3) << 16);
        *(uint2*)(Pw + (size_t)(nt * 16 + nl) * PSTR + mg * 16 + g4 * 4) = w;
    };

    auto compute = [&](Frag& F) {
        f4 sc00 = __builtin_amdgcn_mfma_f32_16x16x32_bf16(F.kf0, qf[0], mkC(F.a00), 0, 0, 0);
        f4 sc01 = __builtin_amdgcn_mfma_f32_16x16x32_bf16(F.kf1, qf[0], mkC(F.a01), 0, 0, 0);
        f4 sc10 = __builtin_amdgcn_mfma_f32_16x16x32_bf16(F.kf0, qf[1], mkC(F.a10), 0, 0, 0);
        f4 sc11 = __builtin_amdgcn_mfma_f32_16x16x32_bf16(F.kf1, qf[1], mkC(F.a11), 0, 0, 0);
        SM(sc00, F.dv0, 0, 0);
        SM(sc01, F.dv1, 0, 1);
        SM(sc10, F.dv0, 1, 0);
        SM(sc11, F.dv1, 1, 1);
        s8v pb0 = *(const s8v*)(Pw + (size_t)(0 * 16 + nl) * PSTR + g4 * 8);
        s8v pb1 = *(const s8v*)(Pw + (size_t)(1 * 16 + nl) * PSTR + g4 * 8);
        pacc[0][0] = __builtin_amdgcn_mfma_f32_16x16x32_bf16(F.vf0, pb0, pacc[0][0], 0, 0, 0);
        pacc[0][1] = __builtin_amdgcn_mfma_f32_16x16x32_bf16(F.vf1, pb0, pacc[0][1], 0, 0, 0);
        pacc[1][0] = __builtin_amdgcn_mfma_f32_16x16x32_bf16(F.vf0, pb1, pacc[1][0], 0, 0, 0);
        pacc[1][1] = __builtin_amdgcn_mfma_f32_16x16x32_bf16(F.vf1, pb1, pacc[1][1], 0, 0, 0);
    };

    const int NC = Nn / 128;
    Frag A, B;
    load(A, 0);
    for (int c = 0; c < NC; c += 2) {
        load(B, c + 1);                    // prefetch while computing A
        compute(A);
        if (c + 2 < NC) load(A, c + 2);    // prefetch while computing B
        compute(B);
    }

    // cross-lane reduce of linear scalars (per n-col: sum over g4 groups)
    #pragma unroll
    for (int nt = 0; nt < 2; ++nt) {
        ps[nt] += __shfl_xor(ps[nt], 16);
        ps[nt] += __shfl_xor(ps[nt], 32);
        prop[nt] += __shfl_xor(prop[nt], 16);
        prop[nt] += __shfl_xor(prop[nt], 32);
    }

    // ---- linear merge across the 4 wh waves, scratch = Pt reinterpreted ----
    float* mrgb = (float*)&Pt[0][0];   // 2 regions x 64 lanes x 20 floats = 10240 B
    __syncthreads();                   // all PV reads of Pt done
    if (wh & 1) {                      // wh 1 -> region 0, wh 3 -> region 1
        float* d = mrgb + ((size_t)(wh >> 1) * 64 + lane) * 20;
        #pragma unroll
        for (int nt = 0; nt < 2; ++nt)
            #pragma unroll
            for (int t = 0; t < 2; ++t)
                #pragma unroll
                for (int r2 = 0; r2 < 4; ++r2) d[nt * 8 + t * 4 + r2] = pacc[nt][t][r2];
        d[16] = ps[0]; d[17] = ps[1]; d[18] = prop[0]; d[19] = prop[1];
    }
    __syncthreads();
    if (!(wh & 1)) {                   // wh 0 += region 0, wh 2 += region 1
        const float* d = mrgb + ((size_t)(wh >> 1) * 64 + lane) * 20;
        #pragma unroll
        for (int nt = 0; nt < 2; ++nt)
            #pragma unroll
            for (int t = 0; t < 2; ++t)
                #pragma unroll
                for (int r2 = 0; r2 < 4; ++r2) pacc[nt][t][r2] += d[nt * 8 + t * 4 + r2];
        ps[0] += d[16]; ps[1] += d[17]; prop[0] += d[18]; prop[1] += d[19];
    }
    __syncthreads();
    if (wh == 2) {
        float* d = mrgb + (size_t)lane * 20;
        #pragma unroll
        for (int nt = 0; nt < 2; ++nt)
            #pragma unroll
            for (int t = 0; t < 2; ++t)
                #pragma unroll
                for (int r2 = 0; r2 < 4; ++r2) d[nt * 8 + t * 4 + r2] = pacc[nt][t][r2];
        d[16] = ps[0]; d[17] = ps[1]; d[18] = prop[0]; d[19] = prop[1];
    }
    __syncthreads();
    if (wh == 0) {
        const float* d = mrgb + (size_t)lane * 20;
        #pragma unroll
        for (int nt = 0; nt < 2; ++nt)
            #pragma unroll
            for (int t = 0; t < 2; ++t)
                #pragma unroll
                for (int r2 = 0; r2 < 4; ++r2) pacc[nt][t][r2] += d[nt * 8 + t * 4 + r2];
        ps[0] += d[16]; ps[1] += d[17]; prop[0] += d[18]; prop[1] += d[19];

        // epilogue: comb(bf16) = feat + attended + 0.1*prop
        #pragma unroll
        for (int nt = 0; nt < 2; ++nt) {
            float invS = 1.f / ps[nt];
            float pp = prop[nt] * invS * 0.1f;
            size_t o = ((size_t)b * Nn + n0w + nt * 16 + nl) * Hh;
            #pragma unroll
            for (int t = 0; t < 2; ++t) {
                f4 fv = *(const f4*)(feat + o + t * 16 + g4 * 4);
                f4 ov = fv + pacc[nt][t] * invS;
                u16x4 cw;
                cw[0] = f2b(ov[0] + pp);
                cw[1] = f2b(ov[1] + pp);
                cw[2] = f2b(ov[2] + pp);
                cw[3] = f2b(ov[3] + pp);
                *(u16x4*)(comb + o + t * 16 + g4 * 4) = cw;
            }
        }
    }
}

// ---------------- output projection + LayerNorm (bf16 comb in) ----------------
__global__ void k_projln(const unsigned short* __restrict__ comb,
                         const float* __restrict__ Wo, const float* __restrict__ bo,
                         const float* __restrict__ gamma, const float* __restrict__ beta,
                         float* __restrict__ out) {
    __shared__ float WoT[Hh][Hh + 1];
    __shared__ float f[8][Hh];
    int tid = threadIdx.x;
    for (int i = tid; i < Hh * Hh; i += 256) {
        WoT[i & 31][i >> 5] = Wo[i];
    }
    int row0 = blockIdx.x * 8;
    f[tid >> 5][tid & 31] = b2f(comb[(size_t)row0 * Hh + tid]);
    __syncthreads();
    int lr = tid >> 5, h = tid & 31;
    float a = bo[h];
    #pragma unroll
    for (int k = 0; k < Hh; ++k) a += f[lr][k] * WoT[k][h];
    float mu = a;
    #pragma unroll
    for (int w = 1; w < 32; w <<= 1) mu += __shfl_xor(mu, w);
    mu *= (1.f / 32.f);
    float d = a - mu;
    float v = d * d;
    #pragma unroll
    for (int w = 1; w < 32; w <<= 1) v += __shfl_xor(v, w);
    v *= (1.f / 32.f);
    out[(size_t)row0 * Hh + tid] = d * rsqrtf(v + LN_EPS) * gamma[h] + beta[h];
}

extern "C" void kernel_launch(void* const* d_in, const int* in_sizes, int n_in,
                              void* d_out, int out_size, void* d_ws, size_t ws_size,
                              hipStream_t stream) {
    const float* x     = (const float*)d_in[0];
    const float* feat  = (const float*)d_in[1];
    const float* dlog  = (const float*)d_in[2];
    const float* Wq    = (const float*)d_in[3];
    const float* bq    = (const float*)d_in[4];
    const float* Wk    = (const float*)d_in[5];
    const float* bk    = (const float*)d_in[6];
    const float* Wv    = (const float*)d_in[7];
    const float* bv    = (const float*)d_in[8];
    const float* adj   = (const float*)d_in[9];
    const float* geo   = (const float*)d_in[10];
    const float* Wo    = (const float*)d_in[11];
    const float* bo    = (const float*)d_in[12];
    const float* gamma = (const float*)d_in[13];
    const float* beta  = (const float*)d_in[14];
    float* out = (float*)d_out;

    char* w = (char*)d_ws;
    unsigned short* Qbf  = (unsigned short*)w;  w += (size_t)Bb * Nn * Hh * 2;
    unsigned short* Kf   = (unsigned short*)w;  w += (size_t)Bb * Nn * Hh * 2;
    unsigned short* Vf   = (unsigned short*)w;  w += (size_t)Bb * Nn * Hh * 2;
    unsigned short* adjF = (unsigned short*)w;  w += (size_t)Nn * Nn * 2;
    float* dsg           = (float*)w;           w += (size_t)Bb * Nn * 4;
    unsigned short* comb = (unsigned short*)w;

    k_adjprep<<<512, 256, 0, stream>>>(adj, geo, adjF);
    k_delayed<<<(Bb * Nn + 255) / 256, 256, 0, stream>>>(x, dlog, dsg);
    k_qkv<<<Bb * Nn / 8, 256, 0, stream>>>(feat, Wq, bq, Wk, bk, Wv, bv, geo, Qbf, Kf, Vf);
    k_attn<<<1024, 256, 0, stream>>>(Qbf, Kf, Vf, adjF, dsg, feat, comb);
    k_projln<<<Bb * Nn / 8, 256, 0, stream>>>(comb, Wo, bo, gamma, beta, out);
}

// Round 10
// 98.718 us; speedup vs baseline: 2.5889x; 2.5889x over previous
//
#include <hip/hip_runtime.h>
#include <hip/hip_bf16.h>
#include <math.h>
#include <stdint.h>

#define Bb 16
#define Tt 28
#define Nn 2048
#define Hh 32
#define LAGS 8
#define LN_EPS 1e-5f
#define PSTR 40                      // P row stride (shorts)

typedef float f4 __attribute__((ext_vector_type(4)));
typedef short s8v __attribute__((ext_vector_type(8)));
typedef unsigned short u16x4 __attribute__((ext_vector_type(4)));
typedef unsigned short u16x8 __attribute__((ext_vector_type(8)));

__device__ __forceinline__ float b2f(unsigned short u) {
    union { unsigned uu; float ff; } x; x.uu = ((unsigned)u) << 16; return x.ff;
}
__device__ __forceinline__ unsigned short f2b(float f) {
    unsigned u = __float_as_uint(f);
    u += 0x7FFFu + ((u >> 16) & 1u);   // RNE
    return (unsigned short)(u >> 16);
}

// ---------- adj fp32 -> bf16 scaled by geo*5, fragment-tile layout (LDS-staged) ----
// adjF[((n>>4)*512 + (m>>2))*64 + (n&15)*4 + (m&3)]
__global__ void k_adjprep(const float* __restrict__ adj, const float* __restrict__ geo_w,
                          unsigned short* __restrict__ adjF) {
    __shared__ float T[16][516];
    float geo = 1.f / (1.f + __expf(-geo_w[0]));
    float cg = geo * 5.f;
    int tid = threadIdx.x;
    int g = blockIdx.x >> 2, q = blockIdx.x & 3;
    int n0 = g * 16, m0 = q * 512;
    #pragma unroll
    for (int r = 0; r < 16; ++r) {
        T[r][tid] = adj[(size_t)(n0 + r) * Nn + m0 + tid];
        T[r][tid + 256] = adj[(size_t)(n0 + r) * Nn + m0 + tid + 256];
    }
    __syncthreads();
    unsigned short* region = adjF + ((size_t)g * 512 + q * 128) * 64;
    #pragma unroll
    for (int i = 0; i < 4; ++i) {
        int e0 = (i * 256 + tid) * 8;
        u16x8 w;
        #pragma unroll
        for (int j = 0; j < 8; ++j) {
            int e = e0 + j;
            int mq = e >> 6, nl = (e >> 2) & 15, mm = e & 3;
            w[j] = f2b(cg * T[nl][mq * 4 + mm]);
        }
        *(u16x8*)(region + e0) = w;
    }
}

// ---------------- delayed signal (f32) ----------------
__global__ void k_delayed(const float* __restrict__ x,
                          const float* __restrict__ dlog,
                          float* __restrict__ dsg) {
    int idx = blockIdx.x * blockDim.x + threadIdx.x; // over B*N
    float w[LAGS];
    float m = -1e30f;
    #pragma unroll
    for (int t = 0; t < LAGS; ++t) m = fmaxf(m, dlog[t]);
    float s = 0.f;
    #pragma unroll
    for (int t = 0; t < LAGS; ++t) { w[t] = __expf(dlog[t] - m); s += w[t]; }
    float inv = 1.f / s;
    if (idx >= Bb * Nn) return;
    int b = idx / Nn, n = idx % Nn;
    float acc = 0.f;
    #pragma unroll
    for (int t = 0; t < LAGS; ++t)
        acc += (w[t] * inv) * x[(size_t)b * Tt * Nn + (size_t)(Tt - 1 - t) * Nn + n];
    dsg[idx] = acc;
}

// ---------- fused QKV: Q (row-major, pre-scaled by cs), K,V fragment layouts ----------
// Kf[((b*128 + (m>>4))*4 + (k>>3))*16 + (m&15)][8]  (k&7 inner)
// Vf[((b*64 + (m>>5))*4 + ((m>>3)&3))*32 + h][8]    (m&7 inner)
__global__ void k_qkv(const float* __restrict__ feat,
                      const float* __restrict__ Wq, const float* __restrict__ bq,
                      const float* __restrict__ Wk, const float* __restrict__ bk,
                      const float* __restrict__ Wv, const float* __restrict__ bv,
                      const float* __restrict__ geo_w,
                      unsigned short* __restrict__ Qbf, unsigned short* __restrict__ Kf,
                      unsigned short* __restrict__ Vf) {
    __shared__ float WqT[Hh][Hh + 1], WkT[Hh][Hh + 1], WvT[Hh][Hh + 1];
    __shared__ float f[8][Hh];
    __shared__ __align__(16) unsigned short VT8[Hh][8];
    int tid = threadIdx.x;
    for (int i = tid; i < Hh * Hh; i += 256) {
        int h = i >> 5, k = i & 31;
        WqT[k][h] = Wq[i];
        WkT[k][h] = Wk[i];
        WvT[k][h] = Wv[i];
    }
    float geo = 1.f / (1.f + __expf(-geo_w[0]));
    float cs = (1.f - geo) * 0.17677669529663687f;   // (1-geo)/sqrt(32)
    int n0 = blockIdx.x * 8;
    f[tid >> 5][tid & 31] = feat[(size_t)n0 * Hh + tid];
    __syncthreads();
    int lr = tid >> 5, h = tid & 31;
    float aq = bq[h], ak = bk[h], av = bv[h];
    #pragma unroll
    for (int k = 0; k < Hh; ++k) {
        float fv = f[lr][k];
        aq += fv * WqT[k][h];
        ak += fv * WkT[k][h];
        av += fv * WvT[k][h];
    }
    Qbf[(size_t)(n0 + lr) * Hh + h] = f2b(aq * cs);
    int b = n0 >> 11, mloc = (n0 & 2047) + lr;
    size_t kaddr = ((((size_t)b * 128 + (mloc >> 4)) * 4 + (h >> 3)) * 16 + (mloc & 15)) * 8 + (h & 7);
    Kf[kaddr] = f2b(ak);
    VT8[h][lr] = f2b(av);
    __syncthreads();
    if (tid < 32) {
        int mloc0 = n0 & 2047;
        size_t vaddr = ((((size_t)b * 64 + (mloc0 >> 5)) * 4 + ((mloc0 >> 3) & 3)) * 32 + tid) * 8;
        *(u16x8*)(Vf + vaddr) = *(const u16x8*)&VT8[tid][0];
    }
}

// ---------------- MFMA attention: 4 waves/block, grid 1024 ------------------------
// Wave wh = wid (0..3) owns the 32-m quarter of each 128-chunk; block owns 32 n-cols.
// Scores: mfma(K_frag, Q_scaled, C = adj_frag) -> __expf -> P (LDS) -> PV mfma.
__global__ __launch_bounds__(256, 4)
void k_attn(const unsigned short* __restrict__ Qbf,
            const unsigned short* __restrict__ Kf,
            const unsigned short* __restrict__ Vf,
            const unsigned short* __restrict__ adjF,
            const float* __restrict__ dsg,
            const float* __restrict__ feat,
            unsigned short* __restrict__ comb) {
    __shared__ __align__(16) unsigned short Pt[4][32 * PSTR];   // 10240 B; reused as merge scratch

    int tid = threadIdx.x;
    int wid = tid >> 6, lane = tid & 63;
    int nl = lane & 15, g4 = lane >> 4;
    int wh = wid;

    // XCD-partitioned swizzle: xcd = bid&7 -> (n-quarter = xcd>>1, batch-half = xcd&1)
    int bid = blockIdx.x;
    int xcd = bid & 7, r = bid >> 3;            // r: 0..127
    int b = ((xcd & 1) << 3) + (r & 7);
    int nt32 = ((xcd >> 1) << 4) + (r >> 3);    // 0..63
    int n0w = nt32 * 32;

    // Q B-fragments (col = n = nl, k = g4*8+j); Q pre-scaled by cs
    s8v qf[2];
    #pragma unroll
    for (int nt = 0; nt < 2; ++nt)
        qf[nt] = *(const s8v*)(Qbf + (((size_t)b * Nn + n0w + nt * 16 + nl) << 5) + g4 * 8);

    f4 pacc[2][2];
    #pragma unroll
    for (int nt = 0; nt < 2; ++nt)
        #pragma unroll
        for (int t = 0; t < 2; ++t) pacc[nt][t] = (f4){0.f, 0.f, 0.f, 0.f};
    float ps[2] = {0.f, 0.f}, prop[2] = {0.f, 0.f};

    const unsigned short* Kb = Kf + (size_t)b * 128 * 4 * 16 * 8;
    const unsigned short* Vb = Vf + (size_t)b * 64 * 4 * 32 * 8;
    const float* dsb = dsg + (size_t)b * Nn;
    unsigned short* Pw = Pt[wid];

    struct Frag {
        s8v kf0, kf1, vf0, vf1;
        f4 dv0, dv1;
        u16x4 a00, a01, a10, a11;
    };

    auto load = [&](Frag& F, int c) {
        int mw = c * 128 + wh * 32;
        F.kf0 = *(const s8v*)(Kb + ((((size_t)(mw >> 4) + 0) * 4 + g4) * 16 + nl) * 8);
        F.kf1 = *(const s8v*)(Kb + ((((size_t)(mw >> 4) + 1) * 4 + g4) * 16 + nl) * 8);
        F.vf0 = *(const s8v*)(Vb + (((size_t)(mw >> 5) * 4 + g4) * 32 + 0 * 16 + nl) * 8);
        F.vf1 = *(const s8v*)(Vb + (((size_t)(mw >> 5) * 4 + g4) * 32 + 1 * 16 + nl) * 8);
        F.dv0 = *(const f4*)(dsb + mw + g4 * 4);
        F.dv1 = *(const f4*)(dsb + mw + 16 + g4 * 4);
        size_t arow0 = (size_t)((n0w >> 4) + 0) * 512 + (mw >> 2);
        size_t arow1 = (size_t)((n0w >> 4) + 1) * 512 + (mw >> 2);
        F.a00 = *(const u16x4*)(adjF + (arow0 + 0 + g4) * 64 + nl * 4);
        F.a01 = *(const u16x4*)(adjF + (arow0 + 4 + g4) * 64 + nl * 4);
        F.a10 = *(const u16x4*)(adjF + (arow1 + 0 + g4) * 64 + nl * 4);
        F.a11 = *(const u16x4*)(adjF + (arow1 + 4 + g4) * 64 + nl * 4);
    };

    auto mkC = [&](u16x4 av) -> f4 {
        f4 C;
        C[0] = b2f(av[0]); C[1] = b2f(av[1]); C[2] = b2f(av[2]); C[3] = b2f(av[3]);
        return C;
    };

    auto SM = [&](f4 sc, f4 dv, int nt, int mg) {
        float p0 = __expf(sc[0]), p1 = __expf(sc[1]);
        float p2 = __expf(sc[2]), p3 = __expf(sc[3]);
        ps[nt] += (p0 + p1) + (p2 + p3);
        prop[nt] += p0 * dv[0] + p1 * dv[1] + p2 * dv[2] + p3 * dv[3];
        uint2 w;
        w.x = (unsigned)f2b(p0) | ((unsigned)f2b(p1) << 16);
        w.y = (unsigned)f2b(p2) | ((unsigned)f2b(p3) << 16);
        *(uint2*)(Pw + (size_t)(nt * 16 + nl) * PSTR + mg * 16 + g4 * 4) = w;
    };

    auto compute = [&](Frag& F) {
        f4 sc00 = __builtin_amdgcn_mfma_f32_16x16x32_bf16(F.kf0, qf[0], mkC(F.a00), 0, 0, 0);
        f4 sc01 = __builtin_amdgcn_mfma_f32_16x16x32_bf16(F.kf1, qf[0], mkC(F.a01), 0, 0, 0);
        f4 sc10 = __builtin_amdgcn_mfma_f32_16x16x32_bf16(F.kf0, qf[1], mkC(F.a10), 0, 0, 0);
        f4 sc11 = __builtin_amdgcn_mfma_f32_16x16x32_bf16(F.kf1, qf[1], mkC(F.a11), 0, 0, 0);
        SM(sc00, F.dv0, 0, 0);
        SM(sc01, F.dv1, 0, 1);
        SM(sc10, F.dv0, 1, 0);
        SM(sc11, F.dv1, 1, 1);
        s8v pb0 = *(const s8v*)(Pw + (size_t)(0 * 16 + nl) * PSTR + g4 * 8);
        s8v pb1 = *(const s8v*)(Pw + (size_t)(1 * 16 + nl) * PSTR + g4 * 8);
        pacc[0][0] = __builtin_amdgcn_mfma_f32_16x16x32_bf16(F.vf0, pb0, pacc[0][0], 0, 0, 0);
        pacc[0][1] = __builtin_amdgcn_mfma_f32_16x16x32_bf16(F.vf1, pb0, pacc[0][1], 0, 0, 0);
        pacc[1][0] = __builtin_amdgcn_mfma_f32_16x16x32_bf16(F.vf0, pb1, pacc[1][0], 0, 0, 0);
        pacc[1][1] = __builtin_amdgcn_mfma_f32_16x16x32_bf16(F.vf1, pb1, pacc[1][1], 0, 0, 0);
    };

    const int NC = Nn / 128;
    Frag A, B;
    load(A, 0);
    for (int c = 0; c < NC; c += 2) {
        load(B, c + 1);                    // prefetch while computing A
        compute(A);
        if (c + 2 < NC) load(A, c + 2);    // prefetch while computing B
        compute(B);
    }

    // cross-lane reduce of linear scalars (per n-col: sum over g4 groups)
    #pragma unroll
    for (int nt = 0; nt < 2; ++nt) {
        ps[nt] += __shfl_xor(ps[nt], 16);
        ps[nt] += __shfl_xor(ps[nt], 32);
        prop[nt] += __shfl_xor(prop[nt], 16);
        prop[nt] += __shfl_xor(prop[nt], 32);
    }

    // ---- linear merge across the 4 wh waves, scratch = Pt reinterpreted ----
    float* mrgb = (float*)&Pt[0][0];   // 2 regions x 64 lanes x 20 floats = 10240 B
    __syncthreads();                   // all PV reads of Pt done
    if (wh & 1) {                      // wh 1 -> region 0, wh 3 -> region 1
        float* d = mrgb + ((size_t)(wh >> 1) * 64 + lane) * 20;
        #pragma unroll
        for (int nt = 0; nt < 2; ++nt)
            #pragma unroll
            for (int t = 0; t < 2; ++t)
                #pragma unroll
                for (int r2 = 0; r2 < 4; ++r2) d[nt * 8 + t * 4 + r2] = pacc[nt][t][r2];
        d[16] = ps[0]; d[17] = ps[1]; d[18] = prop[0]; d[19] = prop[1];
    }
    __syncthreads();
    if (!(wh & 1)) {                   // wh 0 += region 0, wh 2 += region 1
        const float* d = mrgb + ((size_t)(wh >> 1) * 64 + lane) * 20;
        #pragma unroll
        for (int nt = 0; nt < 2; ++nt)
            #pragma unroll
            for (int t = 0; t < 2; ++t)
                #pragma unroll
                for (int r2 = 0; r2 < 4; ++r2) pacc[nt][t][r2] += d[nt * 8 + t * 4 + r2];
        ps[0] += d[16]; ps[1] += d[17]; prop[0] += d[18]; prop[1] += d[19];
    }
    __syncthreads();
    if (wh == 2) {
        float* d = mrgb + (size_t)lane * 20;
        #pragma unroll
        for (int nt = 0; nt < 2; ++nt)
            #pragma unroll
            for (int t = 0; t < 2; ++t)
                #pragma unroll
                for (int r2 = 0; r2 < 4; ++r2) d[nt * 8 + t * 4 + r2] = pacc[nt][t][r2];
        d[16] = ps[0]; d[17] = ps[1]; d[18] = prop[0]; d[19] = prop[1];
    }
    __syncthreads();
    if (wh == 0) {
        const float* d = mrgb + (size_t)lane * 20;
        #pragma unroll
        for (int nt = 0; nt < 2; ++nt)
            #pragma unroll
            for (int t = 0; t < 2; ++t)
                #pragma unroll
                for (int r2 = 0; r2 < 4; ++r2) pacc[nt][t][r2] += d[nt * 8 + t * 4 + r2];
        ps[0] += d[16]; ps[1] += d[17]; prop[0] += d[18]; prop[1] += d[19];

        // epilogue: comb(bf16) = feat + attended + 0.1*prop
        #pragma unroll
        for (int nt = 0; nt < 2; ++nt) {
            float invS = 1.f / ps[nt];
            float pp = prop[nt] * invS * 0.1f;
            size_t o = ((size_t)b * Nn + n0w + nt * 16 + nl) * Hh;
            #pragma unroll
            for (int t = 0; t < 2; ++t) {
                f4 fv = *(const f4*)(feat + o + t * 16 + g4 * 4);
                f4 ov = fv + pacc[nt][t] * invS;
                u16x4 cw;
                cw[0] = f2b(ov[0] + pp);
                cw[1] = f2b(ov[1] + pp);
                cw[2] = f2b(ov[2] + pp);
                cw[3] = f2b(ov[3] + pp);
                *(u16x4*)(comb + o + t * 16 + g4 * 4) = cw;
            }
        }
    }
}

// ---------------- output projection + LayerNorm (bf16 comb in) ----------------
__global__ void k_projln(const unsigned short* __restrict__ comb,
                         const float* __restrict__ Wo, const float* __restrict__ bo,
                         const float* __restrict__ gamma, const float* __restrict__ beta,
                         float* __restrict__ out) {
    __shared__ float WoT[Hh][Hh + 1];
    __shared__ float f[8][Hh];
    int tid = threadIdx.x;
    for (int i = tid; i < Hh * Hh; i += 256) {
        WoT[i & 31][i >> 5] = Wo[i];
    }
    int row0 = blockIdx.x * 8;
    f[tid >> 5][tid & 31] = b2f(comb[(size_t)row0 * Hh + tid]);
    __syncthreads();
    int lr = tid >> 5, h = tid & 31;
    float a = bo[h];
    #pragma unroll
    for (int k = 0; k < Hh; ++k) a += f[lr][k] * WoT[k][h];
    float mu = a;
    #pragma unroll
    for (int w = 1; w < 32; w <<= 1) mu += __shfl_xor(mu, w);
    mu *= (1.f / 32.f);
    float d = a - mu;
    float v = d * d;
    #pragma unroll
    for (int w = 1; w < 32; w <<= 1) v += __shfl_xor(v, w);
    v *= (1.f / 32.f);
    out[(size_t)row0 * Hh + tid] = d * rsqrtf(v + LN_EPS) * gamma[h] + beta[h];
}

extern "C" void kernel_launch(void* const* d_in, const int* in_sizes, int n_in,
                              void* d_out, int out_size, void* d_ws, size_t ws_size,
                              hipStream_t stream) {
    const float* x     = (const float*)d_in[0];
    const float* feat  = (const float*)d_in[1];
    const float* dlog  = (const float*)d_in[2];
    const float* Wq    = (const float*)d_in[3];
    const float* bq    = (const float*)d_in[4];
    const float* Wk    = (const float*)d_in[5];
    const float* bk    = (const float*)d_in[6];
    const float* Wv    = (const float*)d_in[7];
    const float* bv    = (const float*)d_in[8];
    const float* adj   = (const float*)d_in[9];
    const float* geo   = (const float*)d_in[10];
    const float* Wo    = (const float*)d_in[11];
    const float* bo    = (const float*)d_in[12];
    const float* gamma = (const float*)d_in[13];
    const float* beta  = (const float*)d_in[14];
    float* out = (float*)d_out;

    char* w = (char*)d_ws;
    unsigned short* Qbf  = (unsigned short*)w;  w += (size_t)Bb * Nn * Hh * 2;
    unsigned short* Kf   = (unsigned short*)w;  w += (size_t)Bb * Nn * Hh * 2;
    unsigned short* Vf   = (unsigned short*)w;  w += (size_t)Bb * Nn * Hh * 2;
    unsigned short* adjF = (unsigned short*)w;  w += (size_t)Nn * Nn * 2;
    float* dsg           = (float*)w;           w += (size_t)Bb * Nn * 4;
    unsigned short* comb = (unsigned short*)w;

    k_adjprep<<<512, 256, 0, stream>>>(adj, geo, adjF);
    k_delayed<<<(Bb * Nn + 255) / 256, 256, 0, stream>>>(x, dlog, dsg);
    k_qkv<<<Bb * Nn / 8, 256, 0, stream>>>(feat, Wq, bq, Wk, bk, Wv, bv, geo, Qbf, Kf, Vf);
    k_attn<<<1024, 256, 0, stream>>>(Qbf, Kf, Vf, adjF, dsg, feat, comb);
    k_projln<<<Bb * Nn / 8, 256, 0, stream>>>(comb, Wo, bo, gamma, beta, out);
}

// Round 11
// 69.624 us; speedup vs baseline: 3.6707x; 1.4179x over previous
//
#include <hip/hip_runtime.h>
#include <hip/hip_bf16.h>
#include <math.h>
#include <stdint.h>

#define Bb 16
#define Tt 28
#define Nn 2048
#define Hh 32
#define LAGS 8
#define LN_EPS 1e-5f
#define PSTR 40                      // P row stride (shorts)

typedef float f4 __attribute__((ext_vector_type(4)));
typedef short s8v __attribute__((ext_vector_type(8)));
typedef unsigned short u16x4 __attribute__((ext_vector_type(4)));
typedef unsigned short u16x8 __attribute__((ext_vector_type(8)));

__device__ __forceinline__ float b2f(unsigned short u) {
    union { unsigned uu; float ff; } x; x.uu = ((unsigned)u) << 16; return x.ff;
}
__device__ __forceinline__ unsigned short f2b(float f) {
    unsigned u = __float_as_uint(f);
    u += 0x7FFFu + ((u >> 16) & 1u);   // RNE
    return (unsigned short)(u >> 16);
}

// ---------- adj fp32 -> bf16 scaled by geo*5, fragment-tile layout (LDS-staged) ----
// adjF[((n>>4)*512 + (m>>2))*64 + (n&15)*4 + (m&3)]
__global__ void k_adjprep(const float* __restrict__ adj, const float* __restrict__ geo_w,
                          unsigned short* __restrict__ adjF) {
    __shared__ float T[16][516];
    float geo = 1.f / (1.f + __expf(-geo_w[0]));
    float cg = geo * 5.f;
    int tid = threadIdx.x;
    int g = blockIdx.x >> 2, q = blockIdx.x & 3;
    int n0 = g * 16, m0 = q * 512;
    #pragma unroll
    for (int r = 0; r < 16; ++r) {
        T[r][tid] = adj[(size_t)(n0 + r) * Nn + m0 + tid];
        T[r][tid + 256] = adj[(size_t)(n0 + r) * Nn + m0 + tid + 256];
    }
    __syncthreads();
    unsigned short* region = adjF + ((size_t)g * 512 + q * 128) * 64;
    #pragma unroll
    for (int i = 0; i < 4; ++i) {
        int e0 = (i * 256 + tid) * 8;
        u16x8 w;
        #pragma unroll
        for (int j = 0; j < 8; ++j) {
            int e = e0 + j;
            int mq = e >> 6, nl = (e >> 2) & 15, mm = e & 3;
            w[j] = f2b(cg * T[nl][mq * 4 + mm]);
        }
        *(u16x8*)(region + e0) = w;
    }
}

// ---------------- delayed signal (f32) ----------------
__global__ void k_delayed(const float* __restrict__ x,
                          const float* __restrict__ dlog,
                          float* __restrict__ dsg) {
    int idx = blockIdx.x * blockDim.x + threadIdx.x; // over B*N
    float w[LAGS];
    float m = -1e30f;
    #pragma unroll
    for (int t = 0; t < LAGS; ++t) m = fmaxf(m, dlog[t]);
    float s = 0.f;
    #pragma unroll
    for (int t = 0; t < LAGS; ++t) { w[t] = __expf(dlog[t] - m); s += w[t]; }
    float inv = 1.f / s;
    if (idx >= Bb * Nn) return;
    int b = idx / Nn, n = idx % Nn;
    float acc = 0.f;
    #pragma unroll
    for (int t = 0; t < LAGS; ++t)
        acc += (w[t] * inv) * x[(size_t)b * Tt * Nn + (size_t)(Tt - 1 - t) * Nn + n];
    dsg[idx] = acc;
}

// ---------- fused QKV: Q (row-major, pre-scaled by cs), K,V fragment layouts ----------
// Kf[((b*128 + (m>>4))*4 + (k>>3))*16 + (m&15)][8]  (k&7 inner)
// Vf[((b*64 + (m>>5))*4 + ((m>>3)&3))*32 + h][8]    (m&7 inner)
__global__ void k_qkv(const float* __restrict__ feat,
                      const float* __restrict__ Wq, const float* __restrict__ bq,
                      const float* __restrict__ Wk, const float* __restrict__ bk,
                      const float* __restrict__ Wv, const float* __restrict__ bv,
                      const float* __restrict__ geo_w,
                      unsigned short* __restrict__ Qbf, unsigned short* __restrict__ Kf,
                      unsigned short* __restrict__ Vf) {
    __shared__ float WqT[Hh][Hh + 1], WkT[Hh][Hh + 1], WvT[Hh][Hh + 1];
    __shared__ float f[8][Hh];
    __shared__ __align__(16) unsigned short VT8[Hh][8];
    int tid = threadIdx.x;
    for (int i = tid; i < Hh * Hh; i += 256) {
        int h = i >> 5, k = i & 31;
        WqT[k][h] = Wq[i];
        WkT[k][h] = Wk[i];
        WvT[k][h] = Wv[i];
    }
    float geo = 1.f / (1.f + __expf(-geo_w[0]));
    float cs = (1.f - geo) * 0.17677669529663687f;   // (1-geo)/sqrt(32)
    int n0 = blockIdx.x * 8;
    f[tid >> 5][tid & 31] = feat[(size_t)n0 * Hh + tid];
    __syncthreads();
    int lr = tid >> 5, h = tid & 31;
    float aq = bq[h], ak = bk[h], av = bv[h];
    #pragma unroll
    for (int k = 0; k < Hh; ++k) {
        float fv = f[lr][k];
        aq += fv * WqT[k][h];
        ak += fv * WkT[k][h];
        av += fv * WvT[k][h];
    }
    Qbf[(size_t)(n0 + lr) * Hh + h] = f2b(aq * cs);
    int b = n0 >> 11, mloc = (n0 & 2047) + lr;
    size_t kaddr = ((((size_t)b * 128 + (mloc >> 4)) * 4 + (h >> 3)) * 16 + (mloc & 15)) * 8 + (h & 7);
    Kf[kaddr] = f2b(ak);
    VT8[h][lr] = f2b(av);
    __syncthreads();
    if (tid < 32) {
        int mloc0 = n0 & 2047;
        size_t vaddr = ((((size_t)b * 64 + (mloc0 >> 5)) * 4 + ((mloc0 >> 3) & 3)) * 32 + tid) * 8;
        *(u16x8*)(Vf + vaddr) = *(const u16x8*)&VT8[tid][0];
    }
}

// ---------------- MFMA attention: 4 waves/block, grid 1024 ------------------------
// Wave wh = wid (0..3) owns the 32-m quarter of each 128-chunk; block owns 32 n-cols.
// Scores: mfma(K_frag, Q_scaled, C = adj_frag) -> __expf -> P (LDS) -> PV mfma.
// NOTE: no min-waves clamp — (256,4) empirically forced VGPR=64 and spilled 119 MB.
__global__ __launch_bounds__(256)
void k_attn(const unsigned short* __restrict__ Qbf,
            const unsigned short* __restrict__ Kf,
            const unsigned short* __restrict__ Vf,
            const unsigned short* __restrict__ adjF,
            const float* __restrict__ dsg,
            const float* __restrict__ feat,
            unsigned short* __restrict__ comb) {
    __shared__ __align__(16) unsigned short Pt[4][32 * PSTR];   // 10240 B; reused as merge scratch

    int tid = threadIdx.x;
    int wid = tid >> 6, lane = tid & 63;
    int nl = lane & 15, g4 = lane >> 4;
    int wh = wid;

    // XCD-partitioned swizzle: xcd = bid&7 -> (n-quarter = xcd>>1, batch-half = xcd&1)
    int bid = blockIdx.x;
    int xcd = bid & 7, r = bid >> 3;            // r: 0..127
    int b = ((xcd & 1) << 3) + (r & 7);
    int nt32 = ((xcd >> 1) << 4) + (r >> 3);    // 0..63
    int n0w = nt32 * 32;

    // Q B-fragments (col = n = nl, k = g4*8+j); Q pre-scaled by cs
    s8v qf[2];
    #pragma unroll
    for (int nt = 0; nt < 2; ++nt)
        qf[nt] = *(const s8v*)(Qbf + (((size_t)b * Nn + n0w + nt * 16 + nl) << 5) + g4 * 8);

    f4 pacc[2][2];
    #pragma unroll
    for (int nt = 0; nt < 2; ++nt)
        #pragma unroll
        for (int t = 0; t < 2; ++t) pacc[nt][t] = (f4){0.f, 0.f, 0.f, 0.f};
    float ps[2] = {0.f, 0.f}, prop[2] = {0.f, 0.f};

    const unsigned short* Kb = Kf + (size_t)b * 128 * 4 * 16 * 8;
    const unsigned short* Vb = Vf + (size_t)b * 64 * 4 * 32 * 8;
    const float* dsb = dsg + (size_t)b * Nn;
    unsigned short* Pw = Pt[wid];

    struct Frag {
        s8v kf0, kf1, vf0, vf1;
        f4 dv0, dv1;
        u16x4 a00, a01, a10, a11;
    };

    auto load = [&](Frag& F, int c) {
        int mw = c * 128 + wh * 32;
        F.kf0 = *(const s8v*)(Kb + ((((size_t)(mw >> 4) + 0) * 4 + g4) * 16 + nl) * 8);
        F.kf1 = *(const s8v*)(Kb + ((((size_t)(mw >> 4) + 1) * 4 + g4) * 16 + nl) * 8);
        F.vf0 = *(const s8v*)(Vb + (((size_t)(mw >> 5) * 4 + g4) * 32 + 0 * 16 + nl) * 8);
        F.vf1 = *(const s8v*)(Vb + (((size_t)(mw >> 5) * 4 + g4) * 32 + 1 * 16 + nl) * 8);
        F.dv0 = *(const f4*)(dsb + mw + g4 * 4);
        F.dv1 = *(const f4*)(dsb + mw + 16 + g4 * 4);
        size_t arow0 = (size_t)((n0w >> 4) + 0) * 512 + (mw >> 2);
        size_t arow1 = (size_t)((n0w >> 4) + 1) * 512 + (mw >> 2);
        F.a00 = *(const u16x4*)(adjF + (arow0 + 0 + g4) * 64 + nl * 4);
        F.a01 = *(const u16x4*)(adjF + (arow0 + 4 + g4) * 64 + nl * 4);
        F.a10 = *(const u16x4*)(adjF + (arow1 + 0 + g4) * 64 + nl * 4);
        F.a11 = *(const u16x4*)(adjF + (arow1 + 4 + g4) * 64 + nl * 4);
    };

    auto mkC = [&](u16x4 av) -> f4 {
        f4 C;
        C[0] = b2f(av[0]); C[1] = b2f(av[1]); C[2] = b2f(av[2]); C[3] = b2f(av[3]);
        return C;
    };

    auto SM = [&](f4 sc, f4 dv, int nt, int mg) {
        float p0 = __expf(sc[0]), p1 = __expf(sc[1]);
        float p2 = __expf(sc[2]), p3 = __expf(sc[3]);
        ps[nt] += (p0 + p1) + (p2 + p3);
        prop[nt] += p0 * dv[0] + p1 * dv[1] + p2 * dv[2] + p3 * dv[3];
        uint2 w;
        w.x = (unsigned)f2b(p0) | ((unsigned)f2b(p1) << 16);
        w.y = (unsigned)f2b(p2) | ((unsigned)f2b(p3) << 16);
        *(uint2*)(Pw + (size_t)(nt * 16 + nl) * PSTR + mg * 16 + g4 * 4) = w;
    };

    auto compute = [&](Frag& F) {
        f4 sc00 = __builtin_amdgcn_mfma_f32_16x16x32_bf16(F.kf0, qf[0], mkC(F.a00), 0, 0, 0);
        f4 sc01 = __builtin_amdgcn_mfma_f32_16x16x32_bf16(F.kf1, qf[0], mkC(F.a01), 0, 0, 0);
        f4 sc10 = __builtin_amdgcn_mfma_f32_16x16x32_bf16(F.kf0, qf[1], mkC(F.a10), 0, 0, 0);
        f4 sc11 = __builtin_amdgcn_mfma_f32_16x16x32_bf16(F.kf1, qf[1], mkC(F.a11), 0, 0, 0);
        SM(sc00, F.dv0, 0, 0);
        SM(sc01, F.dv1, 0, 1);
        SM(sc10, F.dv0, 1, 0);
        SM(sc11, F.dv1, 1, 1);
        s8v pb0 = *(const s8v*)(Pw + (size_t)(0 * 16 + nl) * PSTR + g4 * 8);
        s8v pb1 = *(const s8v*)(Pw + (size_t)(1 * 16 + nl) * PSTR + g4 * 8);
        pacc[0][0] = __builtin_amdgcn_mfma_f32_16x16x32_bf16(F.vf0, pb0, pacc[0][0], 0, 0, 0);
        pacc[0][1] = __builtin_amdgcn_mfma_f32_16x16x32_bf16(F.vf1, pb0, pacc[0][1], 0, 0, 0);
        pacc[1][0] = __builtin_amdgcn_mfma_f32_16x16x32_bf16(F.vf0, pb1, pacc[1][0], 0, 0, 0);
        pacc[1][1] = __builtin_amdgcn_mfma_f32_16x16x32_bf16(F.vf1, pb1, pacc[1][1], 0, 0, 0);
    };

    const int NC = Nn / 128;
    Frag A, B;
    load(A, 0);
    for (int c = 0; c < NC; c += 2) {
        load(B, c + 1);                    // prefetch while computing A
        compute(A);
        if (c + 2 < NC) load(A, c + 2);    // prefetch while computing B
        compute(B);
    }

    // cross-lane reduce of linear scalars (per n-col: sum over g4 groups)
    #pragma unroll
    for (int nt = 0; nt < 2; ++nt) {
        ps[nt] += __shfl_xor(ps[nt], 16);
        ps[nt] += __shfl_xor(ps[nt], 32);
        prop[nt] += __shfl_xor(prop[nt], 16);
        prop[nt] += __shfl_xor(prop[nt], 32);
    }

    // ---- linear merge across the 4 wh waves, scratch = Pt reinterpreted ----
    float* mrgb = (float*)&Pt[0][0];   // 2 regions x 64 lanes x 20 floats = 10240 B
    __syncthreads();                   // all PV reads of Pt done
    if (wh & 1) {                      // wh 1 -> region 0, wh 3 -> region 1
        float* d = mrgb + ((size_t)(wh >> 1) * 64 + lane) * 20;
        #pragma unroll
        for (int nt = 0; nt < 2; ++nt)
            #pragma unroll
            for (int t = 0; t < 2; ++t)
                #pragma unroll
                for (int r2 = 0; r2 < 4; ++r2) d[nt * 8 + t * 4 + r2] = pacc[nt][t][r2];
        d[16] = ps[0]; d[17] = ps[1]; d[18] = prop[0]; d[19] = prop[1];
    }
    __syncthreads();
    if (!(wh & 1)) {                   // wh 0 += region 0, wh 2 += region 1
        const float* d = mrgb + ((size_t)(wh >> 1) * 64 + lane) * 20;
        #pragma unroll
        for (int nt = 0; nt < 2; ++nt)
            #pragma unroll
            for (int t = 0; t < 2; ++t)
                #pragma unroll
                for (int r2 = 0; r2 < 4; ++r2) pacc[nt][t][r2] += d[nt * 8 + t * 4 + r2];
        ps[0] += d[16]; ps[1] += d[17]; prop[0] += d[18]; prop[1] += d[19];
    }
    __syncthreads();
    if (wh == 2) {
        float* d = mrgb + (size_t)lane * 20;
        #pragma unroll
        for (int nt = 0; nt < 2; ++nt)
            #pragma unroll
            for (int t = 0; t < 2; ++t)
                #pragma unroll
                for (int r2 = 0; r2 < 4; ++r2) d[nt * 8 + t * 4 + r2] = pacc[nt][t][r2];
        d[16] = ps[0]; d[17] = ps[1]; d[18] = prop[0]; d[19] = prop[1];
    }
    __syncthreads();
    if (wh == 0) {
        const float* d = mrgb + (size_t)lane * 20;
        #pragma unroll
        for (int nt = 0; nt < 2; ++nt)
            #pragma unroll
            for (int t = 0; t < 2; ++t)
                #pragma unroll
                for (int r2 = 0; r2 < 4; ++r2) pacc[nt][t][r2] += d[nt * 8 + t * 4 + r2];
        ps[0] += d[16]; ps[1] += d[17]; prop[0] += d[18]; prop[1] += d[19];

        // epilogue: comb(bf16) = feat + attended + 0.1*prop
        #pragma unroll
        for (int nt = 0; nt < 2; ++nt) {
            float invS = 1.f / ps[nt];
            float pp = prop[nt] * invS * 0.1f;
            size_t o = ((size_t)b * Nn + n0w + nt * 16 + nl) * Hh;
            #pragma unroll
            for (int t = 0; t < 2; ++t) {
                f4 fv = *(const f4*)(feat + o + t * 16 + g4 * 4);
                f4 ov = fv + pacc[nt][t] * invS;
                u16x4 cw;
                cw[0] = f2b(ov[0] + pp);
                cw[1] = f2b(ov[1] + pp);
                cw[2] = f2b(ov[2] + pp);
                cw[3] = f2b(ov[3] + pp);
                *(u16x4*)(comb + o + t * 16 + g4 * 4) = cw;
            }
        }
    }
}

// ---------------- output projection + LayerNorm (bf16 comb in) ----------------
__global__ void k_projln(const unsigned short* __restrict__ comb,
                         const float* __restrict__ Wo, const float* __restrict__ bo,
                         const float* __restrict__ gamma, const float* __restrict__ beta,
                         float* __restrict__ out) {
    __shared__ float WoT[Hh][Hh + 1];
    __shared__ float f[8][Hh];
    int tid = threadIdx.x;
    for (int i = tid; i < Hh * Hh; i += 256) {
        WoT[i & 31][i >> 5] = Wo[i];
    }
    int row0 = blockIdx.x * 8;
    f[tid >> 5][tid & 31] = b2f(comb[(size_t)row0 * Hh + tid]);
    __syncthreads();
    int lr = tid >> 5, h = tid & 31;
    float a = bo[h];
    #pragma unroll
    for (int k = 0; k < Hh; ++k) a += f[lr][k] * WoT[k][h];
    float mu = a;
    #pragma unroll
    for (int w = 1; w < 32; w <<= 1) mu += __shfl_xor(mu, w);
    mu *= (1.f / 32.f);
    float d = a - mu;
    float v = d * d;
    #pragma unroll
    for (int w = 1; w < 32; w <<= 1) v += __shfl_xor(v, w);
    v *= (1.f / 32.f);
    out[(size_t)row0 * Hh + tid] = d * rsqrtf(v + LN_EPS) * gamma[h] + beta[h];
}

extern "C" void kernel_launch(void* const* d_in, const int* in_sizes, int n_in,
                              void* d_out, int out_size, void* d_ws, size_t ws_size,
                              hipStream_t stream) {
    const float* x     = (const float*)d_in[0];
    const float* feat  = (const float*)d_in[1];
    const float* dlog  = (const float*)d_in[2];
    const float* Wq    = (const float*)d_in[3];
    const float* bq    = (const float*)d_in[4];
    const float* Wk    = (const float*)d_in[5];
    const float* bk    = (const float*)d_in[6];
    const float* Wv    = (const float*)d_in[7];
    const float* bv    = (const float*)d_in[8];
    const float* adj   = (const float*)d_in[9];
    const float* geo   = (const float*)d_in[10];
    const float* Wo    = (const float*)d_in[11];
    const float* bo    = (const float*)d_in[12];
    const float* gamma = (const float*)d_in[13];
    const float* beta  = (const float*)d_in[14];
    float* out = (float*)d_out;

    char* w = (char*)d_ws;
    unsigned short* Qbf  = (unsigned short*)w;  w += (size_t)Bb * Nn * Hh * 2;
    unsigned short* Kf   = (unsigned short*)w;  w += (size_t)Bb * Nn * Hh * 2;
    unsigned short* Vf   = (unsigned short*)w;  w += (size_t)Bb * Nn * Hh * 2;
    unsigned short* adjF = (unsigned short*)w;  w += (size_t)Nn * Nn * 2;
    float* dsg           = (float*)w;           w += (size_t)Bb * Nn * 4;
    unsigned short* comb = (unsigned short*)w;

    k_adjprep<<<512, 256, 0, stream>>>(adj, geo, adjF);
    k_delayed<<<(Bb * Nn + 255) / 256, 256, 0, stream>>>(x, dlog, dsg);
    k_qkv<<<Bb * Nn / 8, 256, 0, stream>>>(feat, Wq, bq, Wk, bk, Wv, bv, geo, Qbf, Kf, Vf);
    k_attn<<<1024, 256, 0, stream>>>(Qbf, Kf, Vf, adjF, dsg, feat, comb);
    k_projln<<<Bb * Nn / 8, 256, 0, stream>>>(comb, Wo, bo, gamma, beta, out);
}